// Round 1
// baseline (324.667 us; speedup 1.0000x reference)
//
#include <hip/hip_runtime.h>
#include <math.h>

#define D 4096
#define H 64
#define S 64
#define EPS 1e-5f

__device__ __forceinline__ float wave_reduce_sum(float v) {
#pragma unroll
    for (int off = 32; off > 0; off >>= 1) v += __shfl_down(v, off, 64);
    return v;
}

// ---------------- Kernel 1: LayerNorm(x) -> xx; write state1_out; build 4 mix vectors
__global__ __launch_bounds__(1024) void k_ln_mix(
    const float* __restrict__ x, const float* __restrict__ state1,
    const float* __restrict__ tmk, const float* __restrict__ tmv,
    const float* __restrict__ tmr, const float* __restrict__ tmg,
    const float* __restrict__ ln1w, const float* __restrict__ ln1b,
    float* __restrict__ state1_out, float* __restrict__ mix /* [4][D]: r,k,v,g */) {
    __shared__ float red[32];
    __shared__ float mb[2];
    const int tid = threadIdx.x;
    float xv[4];
    float s = 0.f, sq = 0.f;
#pragma unroll
    for (int k = 0; k < 4; ++k) {
        float v = x[k * 1024 + tid];
        xv[k] = v;
        s += v;
        sq += v * v;
    }
    s = wave_reduce_sum(s);
    sq = wave_reduce_sum(sq);
    const int wave = tid >> 6, lane = tid & 63;
    if (lane == 0) { red[wave] = s; red[16 + wave] = sq; }
    __syncthreads();
    if (tid == 0) {
        float ts = 0.f, tq = 0.f;
        for (int i = 0; i < 16; ++i) { ts += red[i]; tq += red[16 + i]; }
        float m = ts / (float)D;
        float var = tq / (float)D - m * m;
        mb[0] = m;
        mb[1] = rsqrtf(var + EPS);
    }
    __syncthreads();
    const float m = mb[0], rs = mb[1];
#pragma unroll
    for (int k = 0; k < 4; ++k) {
        int i = k * 1024 + tid;
        float xx = (xv[k] - m) * rs * ln1w[i] + ln1b[i];
        state1_out[i] = xx;
        float s1 = state1[i];
        float d = xx - s1;
        mix[i]         = s1 + d * tmr[i];
        mix[D + i]     = s1 + d * tmk[i];
        mix[2 * D + i] = s1 + d * tmv[i];
        mix[3 * D + i] = s1 + d * tmg[i];
    }
}

// ---------------- Kernel 2: fused 4x GEMV (Wr,Wk,Wv,Wg) @ their mixes -> rkvg[4][D]
__global__ __launch_bounds__(256) void k_gemv4(
    const float* __restrict__ Wr, const float* __restrict__ Wk,
    const float* __restrict__ Wv, const float* __restrict__ Wg,
    const float* __restrict__ mix, float* __restrict__ rkvg) {
    const int wave = threadIdx.x >> 6, lane = threadIdx.x & 63;
    const int g = blockIdx.x * 4 + wave;       // 0..16383
    const int m = g >> 12;                     // which matrix
    const int row = g & (D - 1);
    const float* W = (m == 0) ? Wr : (m == 1) ? Wk : (m == 2) ? Wv : Wg;
    const float4* wr = (const float4*)(W + (size_t)row * D);
    const float4* vx = (const float4*)(mix + (size_t)m * D);
    float a0 = 0.f, a1 = 0.f, a2 = 0.f, a3 = 0.f;
#pragma unroll
    for (int it = 0; it < 16; ++it) {
        float4 w = wr[it * 64 + lane];
        float4 xv = vx[it * 64 + lane];
        a0 += w.x * xv.x; a1 += w.y * xv.y; a2 += w.z * xv.z; a3 += w.w * xv.w;
    }
    float acc = (a0 + a1) + (a2 + a3);
    acc = wave_reduce_sum(acc);
    if (lane == 0) rkvg[m * D + row] = acc;
}

// ---------------- Kernel 3: per-head kv/wkv/state2 decay + instance norm + SiLU gate -> y
__global__ __launch_bounds__(256) void k_heads(
    const float* __restrict__ rkvg, const float* __restrict__ state2,
    const float* __restrict__ tdecay, const float* __restrict__ tfirst,
    const float* __restrict__ lnxw, const float* __restrict__ lnxb,
    float* __restrict__ state2_out, float* __restrict__ y) {
    __shared__ float part[4][64];
    const int h = blockIdx.x;
    const int wave = threadIdx.x >> 6, j = threadIdx.x & 63;
    const int base = h * S;
    // lane j of every wave holds element j of each per-head vector -> shfl broadcast
    const float rj = rkvg[base + j];
    const float kj = rkvg[D + base + j];
    const float vj = rkvg[2 * D + base + j];
    const float tfj = tfirst[base + j];
    const float tdj = tdecay[base + j];
    const float* s2 = state2 + (size_t)h * S * S;
    float* s2o = state2_out + (size_t)h * S * S;
    float wkv = 0.f;
#pragma unroll
    for (int ii = 0; ii < 16; ++ii) {
        int i = wave * 16 + ii;
        float ri = __shfl(rj, i, 64);
        float ki = __shfl(kj, i, 64);
        float tfi = __shfl(tfj, i, 64);
        float tdi = __shfl(tdj, i, 64);
        float sv = s2[i * S + j];
        float kv = ki * vj;
        wkv += ri * (kv * tfi + sv);
        s2o[i * S + j] = kv + sv * tdi;
    }
    part[wave][j] = wkv;
    __syncthreads();
    if (wave == 0) {
        float w0 = part[0][j] + part[1][j] + part[2][j] + part[3][j];
        float sum = w0, sq = w0 * w0;
#pragma unroll
        for (int off = 1; off < 64; off <<= 1) {
            sum += __shfl_xor(sum, off, 64);
            sq += __shfl_xor(sq, off, 64);
        }
        float mu = sum / (float)S;
        float var = sq / (float)S - mu * mu;
        float xn = (w0 - mu) * rsqrtf(var + EPS);
        float gj = rkvg[3 * D + base + j];
        float gate = gj / (1.f + expf(-gj));
        y[base + j] = (xn * lnxw[base + j] + lnxb[base + j]) * gate;
    }
}

// ---------------- Kernel 4: out = x + Wo @ y
__global__ __launch_bounds__(256) void k_out(
    const float* __restrict__ Wo, const float* __restrict__ y,
    const float* __restrict__ x, float* __restrict__ out) {
    const int wave = threadIdx.x >> 6, lane = threadIdx.x & 63;
    const int row = blockIdx.x * 4 + wave;
    const float4* wr = (const float4*)(Wo + (size_t)row * D);
    const float4* vy = (const float4*)y;
    float a0 = 0.f, a1 = 0.f, a2 = 0.f, a3 = 0.f;
#pragma unroll
    for (int it = 0; it < 16; ++it) {
        float4 w = wr[it * 64 + lane];
        float4 yv = vy[it * 64 + lane];
        a0 += w.x * yv.x; a1 += w.y * yv.y; a2 += w.z * yv.z; a3 += w.w * yv.w;
    }
    float acc = (a0 + a1) + (a2 + a3);
    acc = wave_reduce_sum(acc);
    if (lane == 0) out[row] = x[row] + acc;
}

extern "C" void kernel_launch(void* const* d_in, const int* in_sizes, int n_in,
                              void* d_out, int out_size, void* d_ws, size_t ws_size,
                              hipStream_t stream) {
    const float* x      = (const float*)d_in[0];
    const float* state1 = (const float*)d_in[1];
    const float* state2 = (const float*)d_in[2];
    const float* tmk    = (const float*)d_in[3];
    const float* tmv    = (const float*)d_in[4];
    const float* tmr    = (const float*)d_in[5];
    const float* tmg    = (const float*)d_in[6];
    const float* tdecay = (const float*)d_in[7];
    const float* tfirst = (const float*)d_in[8];
    const float* Wr     = (const float*)d_in[9];
    const float* Wk     = (const float*)d_in[10];
    const float* Wv     = (const float*)d_in[11];
    const float* Wg     = (const float*)d_in[12];
    const float* Wo     = (const float*)d_in[13];
    const float* ln1w   = (const float*)d_in[14];
    const float* ln1b   = (const float*)d_in[15];
    const float* lnxw   = (const float*)d_in[16];
    const float* lnxb   = (const float*)d_in[17];

    float* out        = (float*)d_out;        // [D]
    float* state1_out = out + D;              // [D]
    float* state2_out = out + 2 * D;          // [H*S*S]

    float* mix  = (float*)d_ws;               // [4*D] (r,k,v,g order)
    float* rkvg = mix + 4 * D;                // [4*D]
    float* y    = rkvg + 4 * D;               // [D]

    k_ln_mix<<<1, 1024, 0, stream>>>(x, state1, tmk, tmv, tmr, tmg, ln1w, ln1b,
                                     state1_out, mix);
    k_gemv4<<<4096, 256, 0, stream>>>(Wr, Wk, Wv, Wg, mix, rkvg);
    k_heads<<<64, 256, 0, stream>>>(rkvg, state2, tdecay, tfirst, lnxw, lnxb,
                                    state2_out, y);
    k_out<<<1024, 256, 0, stream>>>(Wo, y, x, out);
}

// Round 2
// 322.759 us; speedup vs baseline: 1.0059x; 1.0059x over previous
//
#include <hip/hip_runtime.h>
#include <math.h>

#define D 4096
#define H 64
#define S 64
#define EPS 1e-5f

__device__ __forceinline__ float wave_reduce_sum(float v) {
#pragma unroll
    for (int off = 32; off > 0; off >>= 1) v += __shfl_down(v, off, 64);
    return v;
}

// ---------------- Kernel 1: LayerNorm(x) -> xx; write state1_out; build 4 mix vectors
__global__ __launch_bounds__(1024) void k_ln_mix(
    const float* __restrict__ x, const float* __restrict__ state1,
    const float* __restrict__ tmk, const float* __restrict__ tmv,
    const float* __restrict__ tmr, const float* __restrict__ tmg,
    const float* __restrict__ ln1w, const float* __restrict__ ln1b,
    float* __restrict__ state1_out, float* __restrict__ mix /* [4][D]: r,k,v,g */) {
    __shared__ float red[32];
    __shared__ float mb[2];
    const int tid = threadIdx.x;
    const float4 xv = ((const float4*)x)[tid];
    float s = (xv.x + xv.y) + (xv.z + xv.w);
    float sq = (xv.x * xv.x + xv.y * xv.y) + (xv.z * xv.z + xv.w * xv.w);
    s = wave_reduce_sum(s);
    sq = wave_reduce_sum(sq);
    const int wave = tid >> 6, lane = tid & 63;
    if (lane == 0) { red[wave] = s; red[16 + wave] = sq; }
    __syncthreads();
    if (tid == 0) {
        float ts = 0.f, tq = 0.f;
        for (int i = 0; i < 16; ++i) { ts += red[i]; tq += red[16 + i]; }
        float m = ts / (float)D;
        float var = tq / (float)D - m * m;
        mb[0] = m;
        mb[1] = rsqrtf(var + EPS);
    }
    __syncthreads();
    const float m = mb[0], rs = mb[1];
    const float4 w4 = ((const float4*)ln1w)[tid];
    const float4 b4 = ((const float4*)ln1b)[tid];
    float4 xx;
    xx.x = (xv.x - m) * rs * w4.x + b4.x;
    xx.y = (xv.y - m) * rs * w4.y + b4.y;
    xx.z = (xv.z - m) * rs * w4.z + b4.z;
    xx.w = (xv.w - m) * rs * w4.w + b4.w;
    ((float4*)state1_out)[tid] = xx;
    const float4 s1 = ((const float4*)state1)[tid];
    float4 d;
    d.x = xx.x - s1.x; d.y = xx.y - s1.y; d.z = xx.z - s1.z; d.w = xx.w - s1.w;
    const float4 tr = ((const float4*)tmr)[tid];
    const float4 tk = ((const float4*)tmk)[tid];
    const float4 tv = ((const float4*)tmv)[tid];
    const float4 tg = ((const float4*)tmg)[tid];
    float4 o;
    o.x = s1.x + d.x * tr.x; o.y = s1.y + d.y * tr.y; o.z = s1.z + d.z * tr.z; o.w = s1.w + d.w * tr.w;
    ((float4*)mix)[tid] = o;
    o.x = s1.x + d.x * tk.x; o.y = s1.y + d.y * tk.y; o.z = s1.z + d.z * tk.z; o.w = s1.w + d.w * tk.w;
    ((float4*)mix)[1024 + tid] = o;
    o.x = s1.x + d.x * tv.x; o.y = s1.y + d.y * tv.y; o.z = s1.z + d.z * tv.z; o.w = s1.w + d.w * tv.w;
    ((float4*)mix)[2048 + tid] = o;
    o.x = s1.x + d.x * tg.x; o.y = s1.y + d.y * tg.y; o.z = s1.z + d.z * tg.z; o.w = s1.w + d.w * tg.w;
    ((float4*)mix)[3072 + tid] = o;
}

// ---------------- Kernel 2: fused 4x GEMV (Wr,Wk,Wv,Wg) @ their mixes -> rkvg[4][D]
// 2 rows per wave, W loads batched 8-deep per row into registers for MLP,
// mix staged in LDS (all 4 waves of a block share the same matrix).
__global__ __launch_bounds__(256) void k_gemv4(
    const float* __restrict__ Wr, const float* __restrict__ Wk,
    const float* __restrict__ Wv, const float* __restrict__ Wg,
    const float* __restrict__ mix, float* __restrict__ rkvg) {
    __shared__ float4 smix[1024];
    const int wave = threadIdx.x >> 6, lane = threadIdx.x & 63;
    const int wg = blockIdx.x * 4 + wave;      // 0..8191
    const int m = wg >> 11;                    // 2048 waves per matrix
    const int r0 = (wg & 2047) * 2;            // row pair within matrix
    const float* W = (m == 0) ? Wr : (m == 1) ? Wk : (m == 2) ? Wv : Wg;
    const float4* vx = (const float4*)mix + (m << 10);
#pragma unroll
    for (int t = 0; t < 4; ++t) smix[t * 256 + threadIdx.x] = vx[t * 256 + threadIdx.x];
    __syncthreads();
    const float4* w0p = (const float4*)W + (size_t)r0 * 1024;
    const float4* w1p = w0p + 1024;
    float a0 = 0.f, a1 = 0.f, b0 = 0.f, b1 = 0.f;
#pragma unroll
    for (int half = 0; half < 2; ++half) {
        float4 wa[8], wb[8];
#pragma unroll
        for (int u = 0; u < 8; ++u) wa[u] = w0p[(half * 8 + u) * 64 + lane];
#pragma unroll
        for (int u = 0; u < 8; ++u) wb[u] = w1p[(half * 8 + u) * 64 + lane];
#pragma unroll
        for (int u = 0; u < 8; ++u) {
            float4 xv = smix[(half * 8 + u) * 64 + lane];
            a0 += wa[u].x * xv.x + wa[u].y * xv.y;
            a1 += wa[u].z * xv.z + wa[u].w * xv.w;
            b0 += wb[u].x * xv.x + wb[u].y * xv.y;
            b1 += wb[u].z * xv.z + wb[u].w * xv.w;
        }
    }
    float a = wave_reduce_sum(a0 + a1);
    float b = wave_reduce_sum(b0 + b1);
    if (lane == 0) {
        rkvg[m * D + r0] = a;
        rkvg[m * D + r0 + 1] = b;
    }
}

// ---------------- Kernel 3: per-head kv/wkv/state2 decay + instance norm + SiLU gate -> y
__global__ __launch_bounds__(1024) void k_heads(
    const float* __restrict__ rkvg, const float* __restrict__ state2,
    const float* __restrict__ tdecay, const float* __restrict__ tfirst,
    const float* __restrict__ lnxw, const float* __restrict__ lnxb,
    float* __restrict__ state2_out, float* __restrict__ y) {
    __shared__ float part[16][64];
    const int h = blockIdx.x;
    const int wave = threadIdx.x >> 6, j = threadIdx.x & 63;
    const int base = h * S;
    const float rj = rkvg[base + j];
    const float kj = rkvg[D + base + j];
    const float vj = rkvg[2 * D + base + j];
    const float tfj = tfirst[base + j];
    const float tdj = tdecay[base + j];
    const float* s2 = state2 + (size_t)h * S * S;
    float* s2o = state2_out + (size_t)h * S * S;
    float sv[4];
#pragma unroll
    for (int ii = 0; ii < 4; ++ii) sv[ii] = s2[(wave * 4 + ii) * S + j];
    float wkv = 0.f;
#pragma unroll
    for (int ii = 0; ii < 4; ++ii) {
        const int i = wave * 4 + ii;
        float ri = __shfl(rj, i, 64);
        float ki = __shfl(kj, i, 64);
        float tfi = __shfl(tfj, i, 64);
        float tdi = __shfl(tdj, i, 64);
        float kv = ki * vj;
        wkv += ri * (kv * tfi + sv[ii]);
        s2o[i * S + j] = kv + sv[ii] * tdi;
    }
    part[wave][j] = wkv;
    __syncthreads();
    if (wave == 0) {
        float w0 = 0.f;
#pragma unroll
        for (int t = 0; t < 16; ++t) w0 += part[t][j];
        float sum = w0, sq = w0 * w0;
#pragma unroll
        for (int off = 1; off < 64; off <<= 1) {
            sum += __shfl_xor(sum, off, 64);
            sq += __shfl_xor(sq, off, 64);
        }
        float mu = sum / (float)S;
        float var = sq / (float)S - mu * mu;
        float xn = (w0 - mu) * rsqrtf(var + EPS);
        float gj = rkvg[3 * D + base + j];
        float gate = gj / (1.f + expf(-gj));
        y[base + j] = (xn * lnxw[base + j] + lnxb[base + j]) * gate;
    }
}

// ---------------- Kernel 4: out = x + Wo @ y  (same MLP structure as k_gemv4)
__global__ __launch_bounds__(256) void k_out(
    const float* __restrict__ Wo, const float* __restrict__ y,
    const float* __restrict__ x, float* __restrict__ out) {
    __shared__ float4 sy[1024];
    const int wave = threadIdx.x >> 6, lane = threadIdx.x & 63;
    const int wg = blockIdx.x * 4 + wave;      // 0..2047
    const int r0 = wg * 2;
    const float4* vy = (const float4*)y;
#pragma unroll
    for (int t = 0; t < 4; ++t) sy[t * 256 + threadIdx.x] = vy[t * 256 + threadIdx.x];
    __syncthreads();
    const float4* w0p = (const float4*)Wo + (size_t)r0 * 1024;
    const float4* w1p = w0p + 1024;
    float a0 = 0.f, a1 = 0.f, b0 = 0.f, b1 = 0.f;
#pragma unroll
    for (int half = 0; half < 2; ++half) {
        float4 wa[8], wb[8];
#pragma unroll
        for (int u = 0; u < 8; ++u) wa[u] = w0p[(half * 8 + u) * 64 + lane];
#pragma unroll
        for (int u = 0; u < 8; ++u) wb[u] = w1p[(half * 8 + u) * 64 + lane];
#pragma unroll
        for (int u = 0; u < 8; ++u) {
            float4 xv = sy[(half * 8 + u) * 64 + lane];
            a0 += wa[u].x * xv.x + wa[u].y * xv.y;
            a1 += wa[u].z * xv.z + wa[u].w * xv.w;
            b0 += wb[u].x * xv.x + wb[u].y * xv.y;
            b1 += wb[u].z * xv.z + wb[u].w * xv.w;
        }
    }
    float a = wave_reduce_sum(a0 + a1);
    float b = wave_reduce_sum(b0 + b1);
    if (lane == 0) {
        out[r0] = x[r0] + a;
        out[r0 + 1] = x[r0 + 1] + b;
    }
}

extern "C" void kernel_launch(void* const* d_in, const int* in_sizes, int n_in,
                              void* d_out, int out_size, void* d_ws, size_t ws_size,
                              hipStream_t stream) {
    const float* x      = (const float*)d_in[0];
    const float* state1 = (const float*)d_in[1];
    const float* state2 = (const float*)d_in[2];
    const float* tmk    = (const float*)d_in[3];
    const float* tmv    = (const float*)d_in[4];
    const float* tmr    = (const float*)d_in[5];
    const float* tmg    = (const float*)d_in[6];
    const float* tdecay = (const float*)d_in[7];
    const float* tfirst = (const float*)d_in[8];
    const float* Wr     = (const float*)d_in[9];
    const float* Wk     = (const float*)d_in[10];
    const float* Wv     = (const float*)d_in[11];
    const float* Wg     = (const float*)d_in[12];
    const float* Wo     = (const float*)d_in[13];
    const float* ln1w   = (const float*)d_in[14];
    const float* ln1b   = (const float*)d_in[15];
    const float* lnxw   = (const float*)d_in[16];
    const float* lnxb   = (const float*)d_in[17];

    float* out        = (float*)d_out;        // [D]
    float* state1_out = out + D;              // [D]
    float* state2_out = out + 2 * D;          // [H*S*S]

    float* mix  = (float*)d_ws;               // [4*D] (r,k,v,g order)
    float* rkvg = mix + 4 * D;                // [4*D]
    float* y    = rkvg + 4 * D;               // [D]

    k_ln_mix<<<1, 1024, 0, stream>>>(x, state1, tmk, tmv, tmr, tmg, ln1w, ln1b,
                                     state1_out, mix);
    k_gemv4<<<2048, 256, 0, stream>>>(Wr, Wk, Wv, Wg, mix, rkvg);
    k_heads<<<64, 1024, 0, stream>>>(rkvg, state2, tdecay, tfirst, lnxw, lnxb,
                                     state2_out, y);
    k_out<<<512, 256, 0, stream>>>(Wo, y, x, out);
}